// Round 15
// baseline (372.845 us; speedup 1.0000x reference)
//
#include <hip/hip_runtime.h>

// SlotAttention MI355X v15 — v14 + parallelism restructure:
// (1) k2 grid (64,32)=2048 blocks, 2 tiles/wave, 4-wave LDS fold (64 partials/b);
// (2) new kr kernel (512 blocks) does partial+den reduction -> upd (k3 no longer
//     scans 16.8MB with 128 blocks); (3) k3 slimmed to @Wv+GRU+MLP+q.
// Workspace: xln@0, qbuf@134217728, wqk@134348800, nump@134414336 (16.8MB),
//   denp@151191552, upd@151322624, sbuf@151584768.

#define NTOT 16384
#define CDIM 128

using short8 = __attribute__((ext_vector_type(8))) short;
using f32x4  = __attribute__((ext_vector_type(4))) float;
using u32x2  = __attribute__((ext_vector_type(2))) unsigned;

__device__ __forceinline__ unsigned pkbf(float lo, float hi) {
  unsigned r;
  asm("v_cvt_pk_bf16_f32 %0, %1, %2" : "=v"(r) : "v"(lo), "v"(hi));
  return r;
}
__device__ __forceinline__ float sigf(float x) { return 1.f / (1.f + __expf(-x)); }
__device__ __forceinline__ float tanhfast(float x) {
  x = fminf(fmaxf(x, -15.f), 15.f);
  float e = __expf(2.f * x);
  return (e - 1.f) / (e + 1.f);
}

// ---- K0: Wqk = Wq @ Wk^T ----
__global__ __launch_bounds__(256) void k0_wqk(const float* __restrict__ Wq,
    const float* __restrict__ Wk, float* __restrict__ wqk) {
  int idx = blockIdx.x * 256 + threadIdx.x;
  int cq = idx >> 7, ck = idx & 127;
  const float* a = Wq + cq * 128;
  const float* b = Wk + ck * 128;
  float s = 0.f;
  #pragma unroll 8
  for (int i = 0; i < 128; i += 4) {
    f32x4 av = *(const f32x4*)(a + i), bv = *(const f32x4*)(b + i);
    s += av[0]*bv[0] + av[1]*bv[1] + av[2]*bv[2] + av[3]*bv[3];
  }
  wqk[idx] = s;
}

// ---- K1: pure LayerNorm stream: x f32 -> xln bf16 [b][n][c] row-major ----
__global__ __launch_bounds__(256) void k1_ln(const float* __restrict__ in,
    const float* __restrict__ gam, const float* __restrict__ bet,
    unsigned short* __restrict__ xln) {
  __shared__ __align__(16) unsigned short xb[64 * 136];
  __shared__ float gs[128], bs[128];
  const int t = threadIdx.x, w = t >> 6, l = t & 63, lr = l & 15, lg = l >> 4;
  if (t < 128) { gs[t] = gam[t]; bs[t] = bet[t]; }
  const long rowbase = (long)blockIdx.x * 64;
  const float* src = in + (rowbase + w * 16 + lr) * CDIM;
  f32x4 x[4][2];
  #pragma unroll
  for (int kb = 0; kb < 4; ++kb) {
    x[kb][0] = *(const f32x4*)(src + kb * 32 + lg * 8);
    x[kb][1] = *(const f32x4*)(src + kb * 32 + lg * 8 + 4);
  }
  float s1 = 0.f, s2 = 0.f;
  #pragma unroll
  for (int kb = 0; kb < 4; ++kb)
    #pragma unroll
    for (int h = 0; h < 2; ++h)
      #pragma unroll
      for (int i = 0; i < 4; ++i) { float xx = x[kb][h][i]; s1 += xx; s2 += xx * xx; }
  s1 += __shfl_xor(s1, 16); s1 += __shfl_xor(s1, 32);
  s2 += __shfl_xor(s2, 16); s2 += __shfl_xor(s2, 32);
  const float mean = s1 * (1.f / 128.f);
  const float rstd = rsqrtf(s2 * (1.f / 128.f) - mean * mean + 1e-5f);
  __syncthreads();
  #pragma unroll
  for (int kb = 0; kb < 4; ++kb) {
    int c0 = kb * 32 + lg * 8;
    union { unsigned uw[4]; short8 s8; } cv;
    #pragma unroll
    for (int p = 0; p < 2; ++p) {
      float y0 = (x[kb][p][0] - mean) * rstd * gs[c0 + p*4 + 0] + bs[c0 + p*4 + 0];
      float y1 = (x[kb][p][1] - mean) * rstd * gs[c0 + p*4 + 1] + bs[c0 + p*4 + 1];
      float y2 = (x[kb][p][2] - mean) * rstd * gs[c0 + p*4 + 2] + bs[c0 + p*4 + 2];
      float y3 = (x[kb][p][3] - mean) * rstd * gs[c0 + p*4 + 3] + bs[c0 + p*4 + 3];
      cv.uw[p*2 + 0] = pkbf(y0, y1);
      cv.uw[p*2 + 1] = pkbf(y2, y3);
    }
    *(short8*)(xb + (w * 16 + lr) * 136 + c0) = cv.s8;
  }
  asm volatile("" ::: "memory");
  unsigned short* dst = xln + (rowbase + w * 16) * CDIM;
  #pragma unroll
  for (int i = 0; i < 4; ++i) {
    int row = i * 4 + (l >> 4), cb = (l & 15) * 8;
    short8 v = *(const short8*)(xb + (w * 16 + row) * 136 + cb);
    *(short8*)(dst + row * CDIM + cb) = v;
  }
}

// ---- Kq: qa = (LN_s(slots) @ Wqk) / sqrt(C) -> bf16 ----
__global__ __launch_bounds__(512) void kq_init(
    const float* __restrict__ slots, const float* __restrict__ lnsg,
    const float* __restrict__ lnsb, const float* __restrict__ wqk,
    unsigned short* __restrict__ qout) {
  const int b = blockIdx.x, t = threadIdx.x;
  const int s = t >> 5, jq = (t & 31) * 4;
  __shared__ __align__(16) float lnq[2048];
  f32x4 x4 = *(const f32x4*)(slots + b * 2048 + t * 4);
  float ps = x4[0] + x4[1] + x4[2] + x4[3];
  float pq = x4[0]*x4[0] + x4[1]*x4[1] + x4[2]*x4[2] + x4[3]*x4[3];
  ps += __shfl_xor(ps, 1); ps += __shfl_xor(ps, 2); ps += __shfl_xor(ps, 4); ps += __shfl_xor(ps, 8); ps += __shfl_xor(ps, 16);
  pq += __shfl_xor(pq, 1); pq += __shfl_xor(pq, 2); pq += __shfl_xor(pq, 4); pq += __shfl_xor(pq, 8); pq += __shfl_xor(pq, 16);
  float mean = ps * (1.f / 128.f);
  float var  = pq * (1.f / 128.f) - mean * mean;
  float rstd = rsqrtf(var + 1e-5f);
  f32x4 l4 = (x4 - mean) * rstd * (*(const f32x4*)(lnsg + jq)) + (*(const f32x4*)(lnsb + jq));
  *(f32x4*)(lnq + t * 4) = l4;
  __syncthreads();
  f32x4 qa = {0.f, 0.f, 0.f, 0.f};
  const float* wqp = wqk + jq;
  const float* qrow = lnq + s * 128;
  for (int c = 0; c < 128; ++c)
    qa += *(const f32x4*)(wqp + c * 128) * qrow[c];
  qa *= 0.08838834764831845f;
  u32x2 pk = { pkbf(qa[0], qa[1]), pkbf(qa[2], qa[3]) };
  *(u32x2*)(qout + b * 2048 + t * 4) = pk;
}

// ---- K2: 2 tiles/wave, coalesced stage -> dots -> softmax -> PV, 4-wave fold --
__global__ __launch_bounds__(256) void k2_attn(
    const unsigned short* __restrict__ xln, const unsigned short* __restrict__ qm,
    float* __restrict__ nump, float* __restrict__ denp) {
  const int nb = blockIdx.x, b = blockIdx.y;  // nb 0..63
  const int t = threadIdx.x, w = t >> 6, l = t & 63, lr = l & 15, lg = l >> 4;
  // smem: per-wave 8KB T x4 | pbuf 4x1280 | denpark 3x16 f32
  __shared__ __align__(16) char smem[38912];
  char* T = smem + w * 8192;
  unsigned short* pbw = (unsigned short*)(smem + 32768) + w * 640;
  float* denpark = (float*)(smem + 32768 + 5120);

  const unsigned short* xb = xln + (long)b * (NTOT * CDIM);
  const unsigned short* qb = qm + b * 2048;

  short8 qf[4];
  #pragma unroll
  for (int kk = 0; kk < 4; ++kk)
    qf[kk] = *(const short8*)(qb + lr * CDIM + kk * 32 + lg * 8);

  f32x4 acc[8];
  #pragma unroll
  for (int i = 0; i < 8; ++i) acc[i] = (f32x4){0.f, 0.f, 0.f, 0.f};
  f32x4 dacc = {0.f, 0.f, 0.f, 0.f};

  short8 g[2][8];
  {
    const unsigned short* ts = xb + (long)(nb * 256 + w * 32) * 128 + l * 8;
    #pragma unroll
    for (int k = 0; k < 8; ++k) g[0][k] = *(const short8*)(ts + k * 512);
  }

  #pragma unroll
  for (int it = 0; it < 2; ++it) {
    const int n0 = nb * 256 + it * 128 + w * 32;
    // stage: lane holds n_loc = k*4+lg, c = lr*8..+7; addr = n_loc*256 + 16*(lr^(n_loc&15))
    #pragma unroll
    for (int k = 0; k < 8; ++k) {
      const unsigned nl = (unsigned)(k * 4 + lg);
      unsigned wr = nl * 256 + ((((unsigned)lr) ^ (nl & 15u)) << 4);
      *(short8*)(T + wr) = g[it][k];
    }
    if (it == 0) {
      const unsigned short* ts = xb + (long)(nb * 256 + 128 + w * 32) * 128 + l * 8;
      #pragma unroll
      for (int k = 0; k < 8; ++k) g[1][k] = *(const short8*)(ts + k * 512);
    }
    asm volatile("" ::: "memory");  // stage writes before frag reads (same-wave in-order)
    short8 xcur[8];
    #pragma unroll
    for (int h = 0; h < 2; ++h)
      #pragma unroll
      for (int kk = 0; kk < 4; ++kk) {
        unsigned rd = (unsigned)((h * 16 + lr) * 256) +
                      ((((unsigned)(kk * 4 + lg)) ^ (unsigned)lr) << 4);
        xcur[h * 4 + kk] = *(const short8*)(T + rd);
      }
    // transpose into xT: byte(c,n) = c*64 + n*2, key (((c>>1)^(c>>3))&3)<<4
    #pragma unroll
    for (int r = 0; r < 8; ++r) {
      const int h = r >> 2, kk = r & 3;
      const unsigned wb = (unsigned)(kk * 2048 + lg * 512 + (h * 16 + lr) * 2);
      #pragma unroll
      for (int e = 0; e < 8; ++e) {
        unsigned key = ((((unsigned)e >> 1) & 3u) ^ (unsigned)lg) << 4;
        unsigned off = (wb + e * 64) ^ key;
        *(unsigned short*)(T + off) = (unsigned short)xcur[r][e];
      }
    }
    // dots: D[s][n] per 16-n half
    #pragma unroll
    for (int h = 0; h < 2; ++h) {
      f32x4 d = {0.f, 0.f, 0.f, 0.f};
      #pragma unroll
      for (int kk = 0; kk < 4; ++kk)
        d = __builtin_amdgcn_mfma_f32_16x16x32_bf16(qf[kk], xcur[h*4+kk], d, 0, 0, 0);
      float e0 = __expf(d[0]), e1 = __expf(d[1]), e2 = __expf(d[2]), e3 = __expf(d[3]);
      float cs = e0 + e1 + e2 + e3;
      cs += __shfl_xor(cs, 16);
      cs += __shfl_xor(cs, 32);
      float inv = 1.f / cs;
      float p0 = e0 * inv + 1e-8f, p1 = e1 * inv + 1e-8f,
            p2 = e2 * inv + 1e-8f, p3 = e3 * inv + 1e-8f;
      dacc[0] += p0; dacc[1] += p1; dacc[2] += p2; dacc[3] += p3;
      unsigned w01 = pkbf(p0, p1), w23 = pkbf(p2, p3);
      const int nn = h * 16 + lr;
      pbw[(lg*4 + 0) * 40 + nn] = (unsigned short)w01;
      pbw[(lg*4 + 1) * 40 + nn] = (unsigned short)(w01 >> 16);
      pbw[(lg*4 + 2) * 40 + nn] = (unsigned short)w23;
      pbw[(lg*4 + 3) * 40 + nn] = (unsigned short)(w23 >> 16);
    }
    asm volatile("" ::: "memory");
    short8 pf = *(const short8*)(pbw + lr * 40 + lg * 8);
    #pragma unroll
    for (int ct = 0; ct < 8; ++ct) {
      unsigned key = (((((unsigned)lr >> 1) & 3u) ^
                      (((unsigned)(ct * 2) + ((unsigned)lr >> 3)) & 3u)) << 4);
      unsigned off = ((unsigned)((ct*16 + lr) * 64 + lg * 16)) ^ key;
      short8 af = *(const short8*)(T + off);
      acc[ct] = __builtin_amdgcn_mfma_f32_16x16x32_bf16(af, pf, acc[ct], 0, 0, 0);
    }
    asm volatile("" ::: "memory");
  }

  // den: reduce over n (lr lanes)
  #pragma unroll
  for (int m = 1; m <= 8; m <<= 1) {
    dacc[0] += __shfl_xor(dacc[0], m); dacc[1] += __shfl_xor(dacc[1], m);
    dacc[2] += __shfl_xor(dacc[2], m); dacc[3] += __shfl_xor(dacc[3], m);
  }
  // waves 1..3 park [s][c] partials in their own (dead) T; wave 0 folds
  if (w > 0) {
    float* rb = (float*)T;
    #pragma unroll
    for (int ct = 0; ct < 8; ++ct)
      *(f32x4*)(rb + lr * 128 + ct * 16 + lg * 4) = acc[ct];
    if (lr == 0) {
      #pragma unroll
      for (int r = 0; r < 4; ++r) denpark[(w - 1) * 16 + lg * 4 + r] = dacc[r];
    }
  }
  __syncthreads();
  if (w == 0) {
    float* outp = nump + (((long)b * 64) + nb) * 2048;
    #pragma unroll
    for (int ct = 0; ct < 8; ++ct) {
      f32x4 sum = acc[ct];
      #pragma unroll
      for (int ww = 1; ww < 4; ++ww)
        sum += *(const f32x4*)((float*)(smem + ww * 8192) + lr * 128 + ct * 16 + lg * 4);
      *(f32x4*)(outp + lr * 128 + ct * 16 + lg * 4) = sum;  // [s][c]
    }
    if (lr == 0) {
      #pragma unroll
      for (int r = 0; r < 4; ++r) {
        float dsum = dacc[r] + denpark[lg * 4 + r] + denpark[16 + lg * 4 + r] +
                     denpark[32 + lg * 4 + r];
        denp[(((long)b * 64) + nb) * 16 + lg * 4 + r] = dsum;
      }
    }
  }
}

// ---- KR: reduce 64 partials + den -> upd[b][s][c] (division folded) ----
__global__ __launch_bounds__(128) void kr_reduce(const float* __restrict__ nump,
    const float* __restrict__ denp, float* __restrict__ upd) {
  const int bs = blockIdx.x;  // b*16 + s
  const int b = bs >> 4, s = bs & 15, t = threadIdx.x;
  __shared__ float dsh;
  if (t < 64) {
    float d = denp[((long)b * 64 + t) * 16 + s];
    d += __shfl_xor(d, 1); d += __shfl_xor(d, 2); d += __shfl_xor(d, 4);
    d += __shfl_xor(d, 8); d += __shfl_xor(d, 16); d += __shfl_xor(d, 32);
    if (t == 0) dsh = d;
  }
  float ns = 0.f;
  const float* np = nump + (long)b * 131072 + s * 128 + t;
  #pragma unroll 4
  for (int p = 0; p < 64; ++p) ns += np[(long)p * 2048];
  __syncthreads();
  upd[b * 2048 + s * 128 + t] = ns / dsh;
}

// ---- K3: upd -> @Wv -> GRU -> MLP -> slots (+ qa next) ----
__global__ __launch_bounds__(128) void k3_update(
    const float* __restrict__ sprev, const float* __restrict__ upd_g,
    const float* __restrict__ Wv,
    const float* __restrict__ wih, const float* __restrict__ whh,
    const float* __restrict__ bih, const float* __restrict__ bhh,
    const float* __restrict__ w1, const float* __restrict__ b1,
    const float* __restrict__ w2, const float* __restrict__ b2,
    const float* __restrict__ lnfg, const float* __restrict__ lnfb,
    const float* __restrict__ lnsg, const float* __restrict__ lnsb,
    const float* __restrict__ wqk,
    float* __restrict__ sout, unsigned short* __restrict__ qout, const int doq) {
  const int g = blockIdx.x, b = blockIdx.y, t = threadIdx.x;
  const int sl = t >> 5, jq = (t & 31) * 4;
  const long base = (long)b * 2048 + g * 512;
  __shared__ __align__(16) float sp[512];
  __shared__ __align__(16) float upd[512];   // nx = num/den (from kr)
  __shared__ __align__(16) float upd2[512];  // updates = nx @ Wv
  __shared__ __align__(16) float lnb[512];

  f32x4 hp4 = *(const f32x4*)(sprev + base + t * 4);
  *(f32x4*)(sp + t * 4) = hp4;
  f32x4 u4 = *(const f32x4*)(upd_g + base + t * 4);
  *(f32x4*)(upd + t * 4) = u4;
  __syncthreads();

  // updates = nx @ Wv
  f32x4 ud = {0,0,0,0};
  const float* nxr = upd + sl * 128;
  for (int c = 0; c < 128; ++c)
    ud += *(const f32x4*)(Wv + c * 128 + jq) * nxr[c];
  *(f32x4*)(upd2 + t * 4) = ud;
  __syncthreads();

  // GRU
  f32x4 ir = {0,0,0,0}, iz = {0,0,0,0}, inn = {0,0,0,0};
  f32x4 hr = {0,0,0,0}, hz = {0,0,0,0}, hn = {0,0,0,0};
  const float* wih_p = wih + jq;
  const float* whh_p = whh + jq;
  const float* ur  = upd2 + sl * 128;
  const float* hrw = sp + sl * 128;
  for (int c = 0; c < 128; ++c) {
    float u = ur[c], h = hrw[c];
    ir  += *(const f32x4*)(wih_p + c * 384)       * u;
    iz  += *(const f32x4*)(wih_p + c * 384 + 128) * u;
    inn += *(const f32x4*)(wih_p + c * 384 + 256) * u;
    hr  += *(const f32x4*)(whh_p + c * 384)       * h;
    hz  += *(const f32x4*)(whh_p + c * 384 + 128) * h;
    hn  += *(const f32x4*)(whh_p + c * 384 + 256) * h;
  }
  ir  += *(const f32x4*)(bih + jq);
  iz  += *(const f32x4*)(bih + 128 + jq);
  inn += *(const f32x4*)(bih + 256 + jq);
  hr  += *(const f32x4*)(bhh + jq);
  hz  += *(const f32x4*)(bhh + 128 + jq);
  hn  += *(const f32x4*)(bhh + 256 + jq);
  f32x4 snew;
  #pragma unroll
  for (int i = 0; i < 4; ++i) {
    float r = sigf(ir[i] + hr[i]);
    float z = sigf(iz[i] + hz[i]);
    float n = tanhfast(inn[i] + r * hn[i]);
    snew[i] = (1.f - z) * n + z * hp4[i];
  }

  float ps = snew[0] + snew[1] + snew[2] + snew[3];
  float pq = snew[0]*snew[0] + snew[1]*snew[1] + snew[2]*snew[2] + snew[3]*snew[3];
  ps += __shfl_xor(ps, 1); ps += __shfl_xor(ps, 2); ps += __shfl_xor(ps, 4); ps += __shfl_xor(ps, 8); ps += __shfl_xor(ps, 16);
  pq += __shfl_xor(pq, 1); pq += __shfl_xor(pq, 2); pq += __shfl_xor(pq, 4); pq += __shfl_xor(pq, 8); pq += __shfl_xor(pq, 16);
  float mean = ps * (1.f / 128.f);
  float var  = pq * (1.f / 128.f) - mean * mean;
  float rstd = rsqrtf(var + 1e-5f);
  f32x4 lf = (snew - mean) * rstd * (*(const f32x4*)(lnfg + jq)) + (*(const f32x4*)(lnfb + jq));
  *(f32x4*)(lnb + t * 4) = lf;
  __syncthreads();

  f32x4 ha = {0,0,0,0};
  const float* w1p = w1 + jq;
  const float* lrow = lnb + sl * 128;
  for (int c = 0; c < 128; ++c)
    ha += *(const f32x4*)(w1p + c * 128) * lrow[c];
  ha += *(const f32x4*)(b1 + jq);
  #pragma unroll
  for (int i = 0; i < 4; ++i) ha[i] = fmaxf(ha[i], 0.f);
  *(f32x4*)(upd + t * 4) = ha;
  __syncthreads();

  f32x4 oa = {0,0,0,0};
  const float* w2p = w2 + jq;
  const float* hrow = upd + sl * 128;
  for (int c = 0; c < 128; ++c)
    oa += *(const f32x4*)(w2p + c * 128) * hrow[c];
  oa += *(const f32x4*)(b2 + jq);
  f32x4 sf = snew + oa;
  *(f32x4*)(sout + base + t * 4) = sf;

  if (doq) {
    float qs = sf[0] + sf[1] + sf[2] + sf[3];
    float qz = sf[0]*sf[0] + sf[1]*sf[1] + sf[2]*sf[2] + sf[3]*sf[3];
    qs += __shfl_xor(qs, 1); qs += __shfl_xor(qs, 2); qs += __shfl_xor(qs, 4); qs += __shfl_xor(qs, 8); qs += __shfl_xor(qs, 16);
    qz += __shfl_xor(qz, 1); qz += __shfl_xor(qz, 2); qz += __shfl_xor(qz, 4); qz += __shfl_xor(qz, 8); qz += __shfl_xor(qz, 16);
    float m2 = qs * (1.f / 128.f);
    float v2 = qz * (1.f / 128.f) - m2 * m2;
    float rs2 = rsqrtf(v2 + 1e-5f);
    f32x4 lq = (sf - m2) * rs2 * (*(const f32x4*)(lnsg + jq)) + (*(const f32x4*)(lnsb + jq));
    *(f32x4*)(sp + t * 4) = lq;
    __syncthreads();
    f32x4 qa = {0,0,0,0};
    const float* wqp = wqk + jq;
    const float* qrow = sp + sl * 128;
    for (int c = 0; c < 128; ++c)
      qa += *(const f32x4*)(wqp + c * 128) * qrow[c];
    qa *= 0.08838834764831845f;
    u32x2 pk = { pkbf(qa[0], qa[1]), pkbf(qa[2], qa[3]) };
    *(u32x2*)(qout + base + t * 4) = pk;
  }
}

extern "C" void kernel_launch(void* const* d_in, const int* in_sizes, int n_in,
                              void* d_out, int out_size, void* d_ws, size_t ws_size,
                              hipStream_t stream) {
  (void)in_sizes; (void)n_in; (void)out_size; (void)ws_size;
  const float* slots = (const float*)d_in[0];
  const float* inputs = (const float*)d_in[1];
  const float* Wq  = (const float*)d_in[2];
  const float* Wk  = (const float*)d_in[3];
  const float* Wv  = (const float*)d_in[4];
  const float* wih = (const float*)d_in[5];
  const float* whh = (const float*)d_in[6];
  const float* bih = (const float*)d_in[7];
  const float* bhh = (const float*)d_in[8];
  const float* w1  = (const float*)d_in[9];
  const float* b1  = (const float*)d_in[10];
  const float* w2  = (const float*)d_in[11];
  const float* b2  = (const float*)d_in[12];
  const float* lnig = (const float*)d_in[13];
  const float* lnib = (const float*)d_in[14];
  const float* lnsg = (const float*)d_in[15];
  const float* lnsb = (const float*)d_in[16];
  const float* lnfg = (const float*)d_in[17];
  const float* lnfb = (const float*)d_in[18];

  char* ws = (char*)d_ws;
  unsigned short* xln  = (unsigned short*)(ws);
  unsigned short* qbuf = (unsigned short*)(ws + 134217728L);
  float* wqk  = (float*)(ws + 134348800L);
  float* nump = (float*)(ws + 134414336L);
  float* denp = (float*)(ws + 151191552L);
  float* updg = (float*)(ws + 151322624L);
  float* sbuf = (float*)(ws + 151584768L);

  k0_wqk<<<64, 256, 0, stream>>>(Wq, Wk, wqk);
  k1_ln<<<8192, 256, 0, stream>>>(inputs, lnig, lnib, xln);
  kq_init<<<32, 512, 0, stream>>>(slots, lnsg, lnsb, wqk, qbuf);
  for (int it = 0; it < 3; ++it) {
    k2_attn<<<dim3(64, 32), 256, 0, stream>>>(xln, qbuf, nump, denp);
    kr_reduce<<<512, 128, 0, stream>>>(nump, denp, updg);
    const float* sprev = (it == 0) ? slots : sbuf;
    float* sdst = (it == 2) ? (float*)d_out : sbuf;
    k3_update<<<dim3(4, 32), 128, 0, stream>>>(sprev, updg, Wv,
                                      wih, whh, bih, bhh, w1, b1, w2, b2,
                                      lnfg, lnfb, lnsg, lnsb, wqk,
                                      sdst, qbuf, (it < 2) ? 1 : 0);
  }
}

// Round 16
// 348.803 us; speedup vs baseline: 1.0689x; 1.0689x over previous
//
#include <hip/hip_runtime.h>

// SlotAttention MI355X v16 — v14 (346.8us, best) with ONE change: k2's g[2][8]
// prefetch double-buffer -> single g[8]. Rationale: v14's ~170 live VGPRs cap
// occupancy at 3 blocks/CU while grid (32,32)=1024 wants 4/CU -> two-generation
// schedule with a 1/3-parallelism tail on the dominant kernel. Single-buffer
// drops peak live regs to ~105 -> 4 waves/SIMD naturally (no launch-bounds
// forcing - R11 lesson), one fully-resident generation. TLP (16 waves/CU)
// replaces the lost load-prefetch ILP.
// Workspace: xln@0, qbuf@134217728, wqk@134348800, nump@134414336 (16.8MB),
//   denp@151191552, sbuf@151322624.

#define NTOT 16384
#define CDIM 128

using short8 = __attribute__((ext_vector_type(8))) short;
using f32x4  = __attribute__((ext_vector_type(4))) float;
using u32x2  = __attribute__((ext_vector_type(2))) unsigned;

__device__ __forceinline__ unsigned pkbf(float lo, float hi) {
  unsigned r;
  asm("v_cvt_pk_bf16_f32 %0, %1, %2" : "=v"(r) : "v"(lo), "v"(hi));
  return r;
}
__device__ __forceinline__ float sigf(float x) { return 1.f / (1.f + __expf(-x)); }
__device__ __forceinline__ float tanhfast(float x) {
  x = fminf(fmaxf(x, -15.f), 15.f);
  float e = __expf(2.f * x);
  return (e - 1.f) / (e + 1.f);
}

// ---- K0: Wqk = Wq @ Wk^T ----
__global__ __launch_bounds__(256) void k0_wqk(const float* __restrict__ Wq,
    const float* __restrict__ Wk, float* __restrict__ wqk) {
  int idx = blockIdx.x * 256 + threadIdx.x;
  int cq = idx >> 7, ck = idx & 127;
  const float* a = Wq + cq * 128;
  const float* b = Wk + ck * 128;
  float s = 0.f;
  #pragma unroll 8
  for (int i = 0; i < 128; i += 4) {
    f32x4 av = *(const f32x4*)(a + i), bv = *(const f32x4*)(b + i);
    s += av[0]*bv[0] + av[1]*bv[1] + av[2]*bv[2] + av[3]*bv[3];
  }
  wqk[idx] = s;
}

// ---- K1: pure LayerNorm stream: x f32 -> xln bf16 [b][n][c] row-major ----
__global__ __launch_bounds__(256) void k1_ln(const float* __restrict__ in,
    const float* __restrict__ gam, const float* __restrict__ bet,
    unsigned short* __restrict__ xln) {
  __shared__ __align__(16) unsigned short xb[64 * 136];
  __shared__ float gs[128], bs[128];
  const int t = threadIdx.x, w = t >> 6, l = t & 63, lr = l & 15, lg = l >> 4;
  if (t < 128) { gs[t] = gam[t]; bs[t] = bet[t]; }
  const long rowbase = (long)blockIdx.x * 64;
  const float* src = in + (rowbase + w * 16 + lr) * CDIM;
  f32x4 x[4][2];
  #pragma unroll
  for (int kb = 0; kb < 4; ++kb) {
    x[kb][0] = *(const f32x4*)(src + kb * 32 + lg * 8);
    x[kb][1] = *(const f32x4*)(src + kb * 32 + lg * 8 + 4);
  }
  float s1 = 0.f, s2 = 0.f;
  #pragma unroll
  for (int kb = 0; kb < 4; ++kb)
    #pragma unroll
    for (int h = 0; h < 2; ++h)
      #pragma unroll
      for (int i = 0; i < 4; ++i) { float xx = x[kb][h][i]; s1 += xx; s2 += xx * xx; }
  s1 += __shfl_xor(s1, 16); s1 += __shfl_xor(s1, 32);
  s2 += __shfl_xor(s2, 16); s2 += __shfl_xor(s2, 32);
  const float mean = s1 * (1.f / 128.f);
  const float rstd = rsqrtf(s2 * (1.f / 128.f) - mean * mean + 1e-5f);
  __syncthreads();
  #pragma unroll
  for (int kb = 0; kb < 4; ++kb) {
    int c0 = kb * 32 + lg * 8;
    union { unsigned uw[4]; short8 s8; } cv;
    #pragma unroll
    for (int p = 0; p < 2; ++p) {
      float y0 = (x[kb][p][0] - mean) * rstd * gs[c0 + p*4 + 0] + bs[c0 + p*4 + 0];
      float y1 = (x[kb][p][1] - mean) * rstd * gs[c0 + p*4 + 1] + bs[c0 + p*4 + 1];
      float y2 = (x[kb][p][2] - mean) * rstd * gs[c0 + p*4 + 2] + bs[c0 + p*4 + 2];
      float y3 = (x[kb][p][3] - mean) * rstd * gs[c0 + p*4 + 3] + bs[c0 + p*4 + 3];
      cv.uw[p*2 + 0] = pkbf(y0, y1);
      cv.uw[p*2 + 1] = pkbf(y2, y3);
    }
    *(short8*)(xb + (w * 16 + lr) * 136 + c0) = cv.s8;
  }
  asm volatile("" ::: "memory");
  unsigned short* dst = xln + (rowbase + w * 16) * CDIM;
  #pragma unroll
  for (int i = 0; i < 4; ++i) {
    int row = i * 4 + (l >> 4), cb = (l & 15) * 8;
    short8 v = *(const short8*)(xb + (w * 16 + row) * 136 + cb);
    *(short8*)(dst + row * CDIM + cb) = v;
  }
}

// ---- Kq: qa = (LN_s(slots) @ Wqk) / sqrt(C) -> bf16 ----
__global__ __launch_bounds__(512) void kq_init(
    const float* __restrict__ slots, const float* __restrict__ lnsg,
    const float* __restrict__ lnsb, const float* __restrict__ wqk,
    unsigned short* __restrict__ qout) {
  const int b = blockIdx.x, t = threadIdx.x;
  const int s = t >> 5, jq = (t & 31) * 4;
  __shared__ __align__(16) float lnq[2048];
  f32x4 x4 = *(const f32x4*)(slots + b * 2048 + t * 4);
  float ps = x4[0] + x4[1] + x4[2] + x4[3];
  float pq = x4[0]*x4[0] + x4[1]*x4[1] + x4[2]*x4[2] + x4[3]*x4[3];
  ps += __shfl_xor(ps, 1); ps += __shfl_xor(ps, 2); ps += __shfl_xor(ps, 4); ps += __shfl_xor(ps, 8); ps += __shfl_xor(ps, 16);
  pq += __shfl_xor(pq, 1); pq += __shfl_xor(pq, 2); pq += __shfl_xor(pq, 4); pq += __shfl_xor(pq, 8); pq += __shfl_xor(pq, 16);
  float mean = ps * (1.f / 128.f);
  float var  = pq * (1.f / 128.f) - mean * mean;
  float rstd = rsqrtf(var + 1e-5f);
  f32x4 l4 = (x4 - mean) * rstd * (*(const f32x4*)(lnsg + jq)) + (*(const f32x4*)(lnsb + jq));
  *(f32x4*)(lnq + t * 4) = l4;
  __syncthreads();
  f32x4 qa = {0.f, 0.f, 0.f, 0.f};
  const float* wqp = wqk + jq;
  const float* qrow = lnq + s * 128;
  for (int c = 0; c < 128; ++c)
    qa += *(const f32x4*)(wqp + c * 128) * qrow[c];
  qa *= 0.08838834764831845f;
  u32x2 pk = { pkbf(qa[0], qa[1]), pkbf(qa[2], qa[3]) };
  *(u32x2*)(qout + b * 2048 + t * 4) = pk;
}

// ---- K2: coalesced stage -> LDS bounce -> dots -> softmax -> p @ xln ----
__global__ __launch_bounds__(256) void k2_attn(
    const unsigned short* __restrict__ xln, const unsigned short* __restrict__ qm,
    float* __restrict__ nump, float* __restrict__ denp) {
  const int nb = blockIdx.x, b = blockIdx.y;
  const int t = threadIdx.x, w = t >> 6, l = t & 63, lr = l & 15, lg = l >> 4;
  __shared__ __align__(16) char smem[38912];
  char* T = smem + w * 8192;
  unsigned short* pbw = (unsigned short*)(smem + 32768) + w * 640;

  const unsigned short* xb = xln + (long)b * (NTOT * CDIM);
  const unsigned short* qb = qm + b * 2048;

  short8 qf[4];
  #pragma unroll
  for (int kk = 0; kk < 4; ++kk)
    qf[kk] = *(const short8*)(qb + lr * CDIM + kk * 32 + lg * 8);

  f32x4 acc[8];
  #pragma unroll
  for (int i = 0; i < 8; ++i) acc[i] = (f32x4){0.f, 0.f, 0.f, 0.f};
  f32x4 dacc = {0.f, 0.f, 0.f, 0.f};

  #pragma unroll
  for (int it = 0; it < 4; ++it) {
    // single-buffer load: tile = contiguous 8KB, lane-linear (1KB/instr)
    short8 g[8];
    {
      const unsigned short* ts = xb + (long)(nb * 512 + (it * 4 + w) * 32) * 128 + l * 8;
      #pragma unroll
      for (int k = 0; k < 8; ++k) g[k] = *(const short8*)(ts + k * 512);
    }
    // stage: lane holds n_loc = k*4+lg, c = lr*8..+7; addr = n_loc*256 + 16*(lr^(n_loc&15))
    #pragma unroll
    for (int k = 0; k < 8; ++k) {
      const unsigned nl = (unsigned)(k * 4 + lg);
      unsigned wr = nl * 256 + ((((unsigned)lr) ^ (nl & 15u)) << 4);
      *(short8*)(T + wr) = g[k];
    }
    asm volatile("" ::: "memory");  // stage writes before frag reads (same-wave in-order)
    short8 xcur[8];
    #pragma unroll
    for (int h = 0; h < 2; ++h)
      #pragma unroll
      for (int kk = 0; kk < 4; ++kk) {
        unsigned rd = (unsigned)((h * 16 + lr) * 256) +
                      ((((unsigned)(kk * 4 + lg)) ^ (unsigned)lr) << 4);
        xcur[h * 4 + kk] = *(const short8*)(T + rd);
      }
    // transpose into xT: byte(c,n) = c*64 + n*2, key (((c>>1)^(c>>3))&3)<<4
    #pragma unroll
    for (int r = 0; r < 8; ++r) {
      const int h = r >> 2, kk = r & 3;
      const unsigned wb = (unsigned)(kk * 2048 + lg * 512 + (h * 16 + lr) * 2);
      #pragma unroll
      for (int e = 0; e < 8; ++e) {
        unsigned key = ((((unsigned)e >> 1) & 3u) ^ (unsigned)lg) << 4;
        unsigned off = (wb + e * 64) ^ key;
        *(unsigned short*)(T + off) = (unsigned short)xcur[r][e];
      }
    }
    // dots: D[s][n] per 16-n half
    #pragma unroll
    for (int h = 0; h < 2; ++h) {
      f32x4 d = {0.f, 0.f, 0.f, 0.f};
      #pragma unroll
      for (int kk = 0; kk < 4; ++kk)
        d = __builtin_amdgcn_mfma_f32_16x16x32_bf16(qf[kk], xcur[h*4+kk], d, 0, 0, 0);
      float e0 = __expf(d[0]), e1 = __expf(d[1]), e2 = __expf(d[2]), e3 = __expf(d[3]);
      float cs = e0 + e1 + e2 + e3;
      cs += __shfl_xor(cs, 16);
      cs += __shfl_xor(cs, 32);
      float inv = 1.f / cs;
      float p0 = e0 * inv + 1e-8f, p1 = e1 * inv + 1e-8f,
            p2 = e2 * inv + 1e-8f, p3 = e3 * inv + 1e-8f;
      dacc[0] += p0; dacc[1] += p1; dacc[2] += p2; dacc[3] += p3;
      unsigned w01 = pkbf(p0, p1), w23 = pkbf(p2, p3);
      const int nn = h * 16 + lr;
      pbw[(lg*4 + 0) * 40 + nn] = (unsigned short)w01;
      pbw[(lg*4 + 1) * 40 + nn] = (unsigned short)(w01 >> 16);
      pbw[(lg*4 + 2) * 40 + nn] = (unsigned short)w23;
      pbw[(lg*4 + 3) * 40 + nn] = (unsigned short)(w23 >> 16);
    }
    asm volatile("" ::: "memory");  // xT/pbuf writes before reads
    short8 pf = *(const short8*)(pbw + lr * 40 + lg * 8);  // B-frag col=s, k=n
    #pragma unroll
    for (int ct = 0; ct < 8; ++ct) {
      unsigned key = (((((unsigned)lr >> 1) & 3u) ^
                      (((unsigned)(ct * 2) + ((unsigned)lr >> 3)) & 3u)) << 4);
      unsigned off = ((unsigned)((ct*16 + lr) * 64 + lg * 16)) ^ key;
      short8 af = *(const short8*)(T + off);
      acc[ct] = __builtin_amdgcn_mfma_f32_16x16x32_bf16(af, pf, acc[ct], 0, 0, 0);
    }
    asm volatile("" ::: "memory");  // PV reads before next tile's stage writes
  }

  // den: reduce over n (lr lanes); all lanes end with den for s=lg*4+r
  #pragma unroll
  for (int m = 1; m <= 8; m <<= 1) {
    dacc[0] += __shfl_xor(dacc[0], m); dacc[1] += __shfl_xor(dacc[1], m);
    dacc[2] += __shfl_xor(dacc[2], m); dacc[3] += __shfl_xor(dacc[3], m);
  }
  __syncthreads();  // all waves done with T/pbuf
  if (w >= 2) {
    float* rb = (float*)(smem + (w - 2) * 8192);
    #pragma unroll
    for (int ct = 0; ct < 8; ++ct)
      *(f32x4*)(rb + lr * 128 + ct * 16 + lg * 4) = acc[ct];
    if (lr == 0) {
      float* db = (float*)(smem + 32768) + (w - 2) * 16;
      #pragma unroll
      for (int r = 0; r < 4; ++r) db[lg * 4 + r] = dacc[r];
    }
  }
  __syncthreads();
  if (w < 2) {
    const float* rb = (float*)(smem + w * 8192);
    float* outp = nump + (((long)b * 32 + nb) * 2 + w) * 2048;
    #pragma unroll
    for (int ct = 0; ct < 8; ++ct) {
      f32x4 other = *(const f32x4*)(rb + lr * 128 + ct * 16 + lg * 4);
      *(f32x4*)(outp + lr * 128 + ct * 16 + lg * 4) = acc[ct] + other;  // [s][c]
    }
    if (lr == 0) {
      const float* db = (float*)(smem + 32768) + w * 16;
      #pragma unroll
      for (int r = 0; r < 4; ++r)
        denp[(((long)b * 32 + nb) * 2 + w) * 16 + lg * 4 + r] =
            dacc[r] + db[lg * 4 + r];
    }
  }
}

// ---- K3: reduce(64) -> /den -> @Wv -> GRU -> MLP -> slots (+ qa next) ----
__global__ __launch_bounds__(128) void k3_update(
    const float* __restrict__ sprev, const float* __restrict__ nump,
    const float* __restrict__ denp, const float* __restrict__ Wv,
    const float* __restrict__ wih, const float* __restrict__ whh,
    const float* __restrict__ bih, const float* __restrict__ bhh,
    const float* __restrict__ w1, const float* __restrict__ b1,
    const float* __restrict__ w2, const float* __restrict__ b2,
    const float* __restrict__ lnfg, const float* __restrict__ lnfb,
    const float* __restrict__ lnsg, const float* __restrict__ lnsb,
    const float* __restrict__ wqk,
    float* __restrict__ sout, unsigned short* __restrict__ qout, const int doq) {
  const int g = blockIdx.x, b = blockIdx.y, t = threadIdx.x;
  const int sl = t >> 5, jq = (t & 31) * 4;
  const int s = g * 4 + sl;
  const long base = (long)b * 2048 + g * 512;
  __shared__ __align__(16) float sp[512];
  __shared__ __align__(16) float upd[512];
  __shared__ __align__(16) float upd2[512];
  __shared__ __align__(16) float lnb[512];
  __shared__ __align__(16) float denred[4];

  if (t < 64) {
    f32x4 dv = *(const f32x4*)(denp + ((long)b * 64 + t) * 16 + g * 4);
    #pragma unroll
    for (int m = 1; m <= 32; m <<= 1) {
      dv[0] += __shfl_xor(dv[0], m); dv[1] += __shfl_xor(dv[1], m);
      dv[2] += __shfl_xor(dv[2], m); dv[3] += __shfl_xor(dv[3], m);
    }
    if (t == 0) *(f32x4*)denred = dv;
  }

  f32x4 hp4 = *(const f32x4*)(sprev + base + t * 4);
  *(f32x4*)(sp + t * 4) = hp4;

  f32x4 ns = {0.f, 0.f, 0.f, 0.f};
  const float* np = nump + (long)b * 131072 + s * 128 + jq;
  #pragma unroll 4
  for (int p = 0; p < 64; ++p) ns += *(const f32x4*)(np + (long)p * 2048);
  __syncthreads();
  *(f32x4*)(upd + t * 4) = ns * (1.f / denred[sl]);
  __syncthreads();

  // updates = nx @ Wv
  f32x4 ud = {0,0,0,0};
  const float* nxr = upd + sl * 128;
  for (int c = 0; c < 128; ++c)
    ud += *(const f32x4*)(Wv + c * 128 + jq) * nxr[c];
  *(f32x4*)(upd2 + t * 4) = ud;
  __syncthreads();

  // GRU
  f32x4 ir = {0,0,0,0}, iz = {0,0,0,0}, inn = {0,0,0,0};
  f32x4 hr = {0,0,0,0}, hz = {0,0,0,0}, hn = {0,0,0,0};
  const float* wih_p = wih + jq;
  const float* whh_p = whh + jq;
  const float* ur  = upd2 + sl * 128;
  const float* hrw = sp + sl * 128;
  for (int c = 0; c < 128; ++c) {
    float u = ur[c], h = hrw[c];
    ir  += *(const f32x4*)(wih_p + c * 384)       * u;
    iz  += *(const f32x4*)(wih_p + c * 384 + 128) * u;
    inn += *(const f32x4*)(wih_p + c * 384 + 256) * u;
    hr  += *(const f32x4*)(whh_p + c * 384)       * h;
    hz  += *(const f32x4*)(whh_p + c * 384 + 128) * h;
    hn  += *(const f32x4*)(whh_p + c * 384 + 256) * h;
  }
  ir  += *(const f32x4*)(bih + jq);
  iz  += *(const f32x4*)(bih + 128 + jq);
  inn += *(const f32x4*)(bih + 256 + jq);
  hr  += *(const f32x4*)(bhh + jq);
  hz  += *(const f32x4*)(bhh + 128 + jq);
  hn  += *(const f32x4*)(bhh + 256 + jq);
  f32x4 snew;
  #pragma unroll
  for (int i = 0; i < 4; ++i) {
    float r = sigf(ir[i] + hr[i]);
    float z = sigf(iz[i] + hz[i]);
    float n = tanhfast(inn[i] + r * hn[i]);
    snew[i] = (1.f - z) * n + z * hp4[i];
  }

  float ps = snew[0] + snew[1] + snew[2] + snew[3];
  float pq = snew[0]*snew[0] + snew[1]*snew[1] + snew[2]*snew[2] + snew[3]*snew[3];
  ps += __shfl_xor(ps, 1); ps += __shfl_xor(ps, 2); ps += __shfl_xor(ps, 4); ps += __shfl_xor(ps, 8); ps += __shfl_xor(ps, 16);
  pq += __shfl_xor(pq, 1); pq += __shfl_xor(pq, 2); pq += __shfl_xor(pq, 4); pq += __shfl_xor(pq, 8); pq += __shfl_xor(pq, 16);
  float mean = ps * (1.f / 128.f);
  float var  = pq * (1.f / 128.f) - mean * mean;
  float rstd = rsqrtf(var + 1e-5f);
  f32x4 lf = (snew - mean) * rstd * (*(const f32x4*)(lnfg + jq)) + (*(const f32x4*)(lnfb + jq));
  *(f32x4*)(lnb + t * 4) = lf;
  __syncthreads();

  f32x4 ha = {0,0,0,0};
  const float* w1p = w1 + jq;
  const float* lrow = lnb + sl * 128;
  for (int c = 0; c < 128; ++c)
    ha += *(const f32x4*)(w1p + c * 128) * lrow[c];
  ha += *(const f32x4*)(b1 + jq);
  #pragma unroll
  for (int i = 0; i < 4; ++i) ha[i] = fmaxf(ha[i], 0.f);
  *(f32x4*)(upd + t * 4) = ha;
  __syncthreads();

  f32x4 oa = {0,0,0,0};
  const float* w2p = w2 + jq;
  const float* hrow = upd + sl * 128;
  for (int c = 0; c < 128; ++c)
    oa += *(const f32x4*)(w2p + c * 128) * hrow[c];
  oa += *(const f32x4*)(b2 + jq);
  f32x4 sf = snew + oa;
  *(f32x4*)(sout + base + t * 4) = sf;

  if (doq) {
    float qs = sf[0] + sf[1] + sf[2] + sf[3];
    float qz = sf[0]*sf[0] + sf[1]*sf[1] + sf[2]*sf[2] + sf[3]*sf[3];
    qs += __shfl_xor(qs, 1); qs += __shfl_xor(qs, 2); qs += __shfl_xor(qs, 4); qs += __shfl_xor(qs, 8); qs += __shfl_xor(qs, 16);
    qz += __shfl_xor(qz, 1); qz += __shfl_xor(qz, 2); qz += __shfl_xor(qz, 4); qz += __shfl_xor(qz, 8); qz += __shfl_xor(qz, 16);
    float m2 = qs * (1.f / 128.f);
    float v2 = qz * (1.f / 128.f) - m2 * m2;
    float rs2 = rsqrtf(v2 + 1e-5f);
    f32x4 lq = (sf - m2) * rs2 * (*(const f32x4*)(lnsg + jq)) + (*(const f32x4*)(lnsb + jq));
    *(f32x4*)(sp + t * 4) = lq;
    __syncthreads();
    f32x4 qa = {0,0,0,0};
    const float* wqp = wqk + jq;
    const float* qrow = sp + sl * 128;
    for (int c = 0; c < 128; ++c)
      qa += *(const f32x4*)(wqp + c * 128) * qrow[c];
    qa *= 0.08838834764831845f;
    u32x2 pk = { pkbf(qa[0], qa[1]), pkbf(qa[2], qa[3]) };
    *(u32x2*)(qout + base + t * 4) = pk;
  }
}

extern "C" void kernel_launch(void* const* d_in, const int* in_sizes, int n_in,
                              void* d_out, int out_size, void* d_ws, size_t ws_size,
                              hipStream_t stream) {
  (void)in_sizes; (void)n_in; (void)out_size; (void)ws_size;
  const float* slots = (const float*)d_in[0];
  const float* inputs = (const float*)d_in[1];
  const float* Wq  = (const float*)d_in[2];
  const float* Wk  = (const float*)d_in[3];
  const float* Wv  = (const float*)d_in[4];
  const float* wih = (const float*)d_in[5];
  const float* whh = (const float*)d_in[6];
  const float* bih = (const float*)d_in[7];
  const float* bhh = (const float*)d_in[8];
  const float* w1  = (const float*)d_in[9];
  const float* b1  = (const float*)d_in[10];
  const float* w2  = (const float*)d_in[11];
  const float* b2  = (const float*)d_in[12];
  const float* lnig = (const float*)d_in[13];
  const float* lnib = (const float*)d_in[14];
  const float* lnsg = (const float*)d_in[15];
  const float* lnsb = (const float*)d_in[16];
  const float* lnfg = (const float*)d_in[17];
  const float* lnfb = (const float*)d_in[18];

  char* ws = (char*)d_ws;
  unsigned short* xln  = (unsigned short*)(ws);
  unsigned short* qbuf = (unsigned short*)(ws + 134217728L);
  float* wqk  = (float*)(ws + 134348800L);
  float* nump = (float*)(ws + 134414336L);
  float* denp = (float*)(ws + 151191552L);
  float* sbuf = (float*)(ws + 151322624L);

  k0_wqk<<<64, 256, 0, stream>>>(Wq, Wk, wqk);
  k1_ln<<<8192, 256, 0, stream>>>(inputs, lnig, lnib, xln);
  kq_init<<<32, 512, 0, stream>>>(slots, lnsg, lnsb, wqk, qbuf);
  for (int it = 0; it < 3; ++it) {
    k2_attn<<<dim3(32, 32), 256, 0, stream>>>(xln, qbuf, nump, denp);
    const float* sprev = (it == 0) ? slots : sbuf;
    float* sdst = (it == 2) ? (float*)d_out : sbuf;
    k3_update<<<dim3(4, 32), 128, 0, stream>>>(sprev, nump, denp, Wv,
                                      wih, whh, bih, bhh, w1, b1, w2, b2,
                                      lnfg, lnfb, lnsg, lnsb, wqk,
                                      sdst, qbuf, (it < 2) ? 1 : 0);
  }
}

// Round 17
// 345.751 us; speedup vs baseline: 1.0784x; 1.0088x over previous
//
#include <hip/hip_runtime.h>

// SlotAttention MI355X v17 — v16 (348.8us) with ONE change: k1 rewritten as a
// fully-coalesced LDS-free LN stream. Old k1 kept MFMA-era fragment-order
// loads: each instr touched 16 rows x 4 col-groups = 64 scattered segments.
// New k1: lane-linear f32x4 loads (1KB contiguous/instr, 2 rows), row stats
// via 5x shfl_xor per 32-lane half, u32x2 stores (2x256B contiguous/instr).
// Workspace: xln@0, qbuf@134217728, wqk@134348800, nump@134414336 (16.8MB),
//   denp@151191552, sbuf@151322624.

#define NTOT 16384
#define CDIM 128

using short8 = __attribute__((ext_vector_type(8))) short;
using f32x4  = __attribute__((ext_vector_type(4))) float;
using u32x2  = __attribute__((ext_vector_type(2))) unsigned;

__device__ __forceinline__ unsigned pkbf(float lo, float hi) {
  unsigned r;
  asm("v_cvt_pk_bf16_f32 %0, %1, %2" : "=v"(r) : "v"(lo), "v"(hi));
  return r;
}
__device__ __forceinline__ float sigf(float x) { return 1.f / (1.f + __expf(-x)); }
__device__ __forceinline__ float tanhfast(float x) {
  x = fminf(fmaxf(x, -15.f), 15.f);
  float e = __expf(2.f * x);
  return (e - 1.f) / (e + 1.f);
}

// ---- K0: Wqk = Wq @ Wk^T ----
__global__ __launch_bounds__(256) void k0_wqk(const float* __restrict__ Wq,
    const float* __restrict__ Wk, float* __restrict__ wqk) {
  int idx = blockIdx.x * 256 + threadIdx.x;
  int cq = idx >> 7, ck = idx & 127;
  const float* a = Wq + cq * 128;
  const float* b = Wk + ck * 128;
  float s = 0.f;
  #pragma unroll 8
  for (int i = 0; i < 128; i += 4) {
    f32x4 av = *(const f32x4*)(a + i), bv = *(const f32x4*)(b + i);
    s += av[0]*bv[0] + av[1]*bv[1] + av[2]*bv[2] + av[3]*bv[3];
  }
  wqk[idx] = s;
}

// ---- K1: fully-coalesced LDS-free LayerNorm stream ----
// Block = 256 threads = 4 waves; wave w owns rows w*16..+15 (8 instrs, 2 rows ea).
__global__ __launch_bounds__(256) void k1_ln(const float* __restrict__ in,
    const float* __restrict__ gam, const float* __restrict__ bet,
    unsigned short* __restrict__ xln) {
  const int t = threadIdx.x, w = t >> 6, l = t & 63;
  const int lc = l & 31, lh = l >> 5;          // col-group, row-half
  const long rowbase = (long)blockIdx.x * 64 + w * 16;
  const f32x4 g4 = *(const f32x4*)(gam + lc * 4);
  const f32x4 b4 = *(const f32x4*)(bet + lc * 4);
  const float* src = in + rowbase * CDIM;      // wave's 16 rows, 8KB contiguous
  unsigned short* dst = xln + rowbase * CDIM;

  #pragma unroll
  for (int i = 0; i < 8; ++i) {
    f32x4 x = *(const f32x4*)(src + i * 256 + l * 4);   // 1KB contiguous/instr
    float s1 = x[0] + x[1] + x[2] + x[3];
    float s2 = x[0]*x[0] + x[1]*x[1] + x[2]*x[2] + x[3]*x[3];
    s1 += __shfl_xor(s1, 1); s1 += __shfl_xor(s1, 2); s1 += __shfl_xor(s1, 4);
    s1 += __shfl_xor(s1, 8); s1 += __shfl_xor(s1, 16);
    s2 += __shfl_xor(s2, 1); s2 += __shfl_xor(s2, 2); s2 += __shfl_xor(s2, 4);
    s2 += __shfl_xor(s2, 8); s2 += __shfl_xor(s2, 16);
    const float mean = s1 * (1.f / 128.f);
    const float rstd = rsqrtf(s2 * (1.f / 128.f) - mean * mean + 1e-5f);
    float y0 = (x[0] - mean) * rstd * g4[0] + b4[0];
    float y1 = (x[1] - mean) * rstd * g4[1] + b4[1];
    float y2 = (x[2] - mean) * rstd * g4[2] + b4[2];
    float y3 = (x[3] - mean) * rstd * g4[3] + b4[3];
    u32x2 pk = { pkbf(y0, y1), pkbf(y2, y3) };
    // row = 2i + lh, col = lc*4: lanes 0-31 -> 256B contig, 32-63 -> next row
    *(u32x2*)(dst + (i * 2 + lh) * CDIM + lc * 4) = pk;
  }
}

// ---- Kq: qa = (LN_s(slots) @ Wqk) / sqrt(C) -> bf16 ----
__global__ __launch_bounds__(512) void kq_init(
    const float* __restrict__ slots, const float* __restrict__ lnsg,
    const float* __restrict__ lnsb, const float* __restrict__ wqk,
    unsigned short* __restrict__ qout) {
  const int b = blockIdx.x, t = threadIdx.x;
  const int s = t >> 5, jq = (t & 31) * 4;
  __shared__ __align__(16) float lnq[2048];
  f32x4 x4 = *(const f32x4*)(slots + b * 2048 + t * 4);
  float ps = x4[0] + x4[1] + x4[2] + x4[3];
  float pq = x4[0]*x4[0] + x4[1]*x4[1] + x4[2]*x4[2] + x4[3]*x4[3];
  ps += __shfl_xor(ps, 1); ps += __shfl_xor(ps, 2); ps += __shfl_xor(ps, 4); ps += __shfl_xor(ps, 8); ps += __shfl_xor(ps, 16);
  pq += __shfl_xor(pq, 1); pq += __shfl_xor(pq, 2); pq += __shfl_xor(pq, 4); pq += __shfl_xor(pq, 8); pq += __shfl_xor(pq, 16);
  float mean = ps * (1.f / 128.f);
  float var  = pq * (1.f / 128.f) - mean * mean;
  float rstd = rsqrtf(var + 1e-5f);
  f32x4 l4 = (x4 - mean) * rstd * (*(const f32x4*)(lnsg + jq)) + (*(const f32x4*)(lnsb + jq));
  *(f32x4*)(lnq + t * 4) = l4;
  __syncthreads();
  f32x4 qa = {0.f, 0.f, 0.f, 0.f};
  const float* wqp = wqk + jq;
  const float* qrow = lnq + s * 128;
  for (int c = 0; c < 128; ++c)
    qa += *(const f32x4*)(wqp + c * 128) * qrow[c];
  qa *= 0.08838834764831845f;
  u32x2 pk = { pkbf(qa[0], qa[1]), pkbf(qa[2], qa[3]) };
  *(u32x2*)(qout + b * 2048 + t * 4) = pk;
}

// ---- K2: coalesced stage -> LDS bounce -> dots -> softmax -> p @ xln ----
__global__ __launch_bounds__(256) void k2_attn(
    const unsigned short* __restrict__ xln, const unsigned short* __restrict__ qm,
    float* __restrict__ nump, float* __restrict__ denp) {
  const int nb = blockIdx.x, b = blockIdx.y;
  const int t = threadIdx.x, w = t >> 6, l = t & 63, lr = l & 15, lg = l >> 4;
  __shared__ __align__(16) char smem[38912];
  char* T = smem + w * 8192;
  unsigned short* pbw = (unsigned short*)(smem + 32768) + w * 640;

  const unsigned short* xb = xln + (long)b * (NTOT * CDIM);
  const unsigned short* qb = qm + b * 2048;

  short8 qf[4];
  #pragma unroll
  for (int kk = 0; kk < 4; ++kk)
    qf[kk] = *(const short8*)(qb + lr * CDIM + kk * 32 + lg * 8);

  f32x4 acc[8];
  #pragma unroll
  for (int i = 0; i < 8; ++i) acc[i] = (f32x4){0.f, 0.f, 0.f, 0.f};
  f32x4 dacc = {0.f, 0.f, 0.f, 0.f};

  #pragma unroll
  for (int it = 0; it < 4; ++it) {
    short8 g[8];
    {
      const unsigned short* ts = xb + (long)(nb * 512 + (it * 4 + w) * 32) * 128 + l * 8;
      #pragma unroll
      for (int k = 0; k < 8; ++k) g[k] = *(const short8*)(ts + k * 512);
    }
    #pragma unroll
    for (int k = 0; k < 8; ++k) {
      const unsigned nl = (unsigned)(k * 4 + lg);
      unsigned wr = nl * 256 + ((((unsigned)lr) ^ (nl & 15u)) << 4);
      *(short8*)(T + wr) = g[k];
    }
    asm volatile("" ::: "memory");
    short8 xcur[8];
    #pragma unroll
    for (int h = 0; h < 2; ++h)
      #pragma unroll
      for (int kk = 0; kk < 4; ++kk) {
        unsigned rd = (unsigned)((h * 16 + lr) * 256) +
                      ((((unsigned)(kk * 4 + lg)) ^ (unsigned)lr) << 4);
        xcur[h * 4 + kk] = *(const short8*)(T + rd);
      }
    #pragma unroll
    for (int r = 0; r < 8; ++r) {
      const int h = r >> 2, kk = r & 3;
      const unsigned wb = (unsigned)(kk * 2048 + lg * 512 + (h * 16 + lr) * 2);
      #pragma unroll
      for (int e = 0; e < 8; ++e) {
        unsigned key = ((((unsigned)e >> 1) & 3u) ^ (unsigned)lg) << 4;
        unsigned off = (wb + e * 64) ^ key;
        *(unsigned short*)(T + off) = (unsigned short)xcur[r][e];
      }
    }
    #pragma unroll
    for (int h = 0; h < 2; ++h) {
      f32x4 d = {0.f, 0.f, 0.f, 0.f};
      #pragma unroll
      for (int kk = 0; kk < 4; ++kk)
        d = __builtin_amdgcn_mfma_f32_16x16x32_bf16(qf[kk], xcur[h*4+kk], d, 0, 0, 0);
      float e0 = __expf(d[0]), e1 = __expf(d[1]), e2 = __expf(d[2]), e3 = __expf(d[3]);
      float cs = e0 + e1 + e2 + e3;
      cs += __shfl_xor(cs, 16);
      cs += __shfl_xor(cs, 32);
      float inv = 1.f / cs;
      float p0 = e0 * inv + 1e-8f, p1 = e1 * inv + 1e-8f,
            p2 = e2 * inv + 1e-8f, p3 = e3 * inv + 1e-8f;
      dacc[0] += p0; dacc[1] += p1; dacc[2] += p2; dacc[3] += p3;
      unsigned w01 = pkbf(p0, p1), w23 = pkbf(p2, p3);
      const int nn = h * 16 + lr;
      pbw[(lg*4 + 0) * 40 + nn] = (unsigned short)w01;
      pbw[(lg*4 + 1) * 40 + nn] = (unsigned short)(w01 >> 16);
      pbw[(lg*4 + 2) * 40 + nn] = (unsigned short)w23;
      pbw[(lg*4 + 3) * 40 + nn] = (unsigned short)(w23 >> 16);
    }
    asm volatile("" ::: "memory");
    short8 pf = *(const short8*)(pbw + lr * 40 + lg * 8);
    #pragma unroll
    for (int ct = 0; ct < 8; ++ct) {
      unsigned key = (((((unsigned)lr >> 1) & 3u) ^
                      (((unsigned)(ct * 2) + ((unsigned)lr >> 3)) & 3u)) << 4);
      unsigned off = ((unsigned)((ct*16 + lr) * 64 + lg * 16)) ^ key;
      short8 af = *(const short8*)(T + off);
      acc[ct] = __builtin_amdgcn_mfma_f32_16x16x32_bf16(af, pf, acc[ct], 0, 0, 0);
    }
    asm volatile("" ::: "memory");
  }

  #pragma unroll
  for (int m = 1; m <= 8; m <<= 1) {
    dacc[0] += __shfl_xor(dacc[0], m); dacc[1] += __shfl_xor(dacc[1], m);
    dacc[2] += __shfl_xor(dacc[2], m); dacc[3] += __shfl_xor(dacc[3], m);
  }
  __syncthreads();
  if (w >= 2) {
    float* rb = (float*)(smem + (w - 2) * 8192);
    #pragma unroll
    for (int ct = 0; ct < 8; ++ct)
      *(f32x4*)(rb + lr * 128 + ct * 16 + lg * 4) = acc[ct];
    if (lr == 0) {
      float* db = (float*)(smem + 32768) + (w - 2) * 16;
      #pragma unroll
      for (int r = 0; r < 4; ++r) db[lg * 4 + r] = dacc[r];
    }
  }
  __syncthreads();
  if (w < 2) {
    const float* rb = (float*)(smem + w * 8192);
    float* outp = nump + (((long)b * 32 + nb) * 2 + w) * 2048;
    #pragma unroll
    for (int ct = 0; ct < 8; ++ct) {
      f32x4 other = *(const f32x4*)(rb + lr * 128 + ct * 16 + lg * 4);
      *(f32x4*)(outp + lr * 128 + ct * 16 + lg * 4) = acc[ct] + other;
    }
    if (lr == 0) {
      const float* db = (float*)(smem + 32768) + w * 16;
      #pragma unroll
      for (int r = 0; r < 4; ++r)
        denp[(((long)b * 32 + nb) * 2 + w) * 16 + lg * 4 + r] =
            dacc[r] + db[lg * 4 + r];
    }
  }
}

// ---- K3: reduce(64) -> /den -> @Wv -> GRU -> MLP -> slots (+ qa next) ----
__global__ __launch_bounds__(128) void k3_update(
    const float* __restrict__ sprev, const float* __restrict__ nump,
    const float* __restrict__ denp, const float* __restrict__ Wv,
    const float* __restrict__ wih, const float* __restrict__ whh,
    const float* __restrict__ bih, const float* __restrict__ bhh,
    const float* __restrict__ w1, const float* __restrict__ b1,
    const float* __restrict__ w2, const float* __restrict__ b2,
    const float* __restrict__ lnfg, const float* __restrict__ lnfb,
    const float* __restrict__ lnsg, const float* __restrict__ lnsb,
    const float* __restrict__ wqk,
    float* __restrict__ sout, unsigned short* __restrict__ qout, const int doq) {
  const int g = blockIdx.x, b = blockIdx.y, t = threadIdx.x;
  const int sl = t >> 5, jq = (t & 31) * 4;
  const int s = g * 4 + sl;
  const long base = (long)b * 2048 + g * 512;
  __shared__ __align__(16) float sp[512];
  __shared__ __align__(16) float upd[512];
  __shared__ __align__(16) float upd2[512];
  __shared__ __align__(16) float lnb[512];
  __shared__ __align__(16) float denred[4];

  if (t < 64) {
    f32x4 dv = *(const f32x4*)(denp + ((long)b * 64 + t) * 16 + g * 4);
    #pragma unroll
    for (int m = 1; m <= 32; m <<= 1) {
      dv[0] += __shfl_xor(dv[0], m); dv[1] += __shfl_xor(dv[1], m);
      dv[2] += __shfl_xor(dv[2], m); dv[3] += __shfl_xor(dv[3], m);
    }
    if (t == 0) *(f32x4*)denred = dv;
  }

  f32x4 hp4 = *(const f32x4*)(sprev + base + t * 4);
  *(f32x4*)(sp + t * 4) = hp4;

  f32x4 ns = {0.f, 0.f, 0.f, 0.f};
  const float* np = nump + (long)b * 131072 + s * 128 + jq;
  #pragma unroll 4
  for (int p = 0; p < 64; ++p) ns += *(const f32x4*)(np + (long)p * 2048);
  __syncthreads();
  *(f32x4*)(upd + t * 4) = ns * (1.f / denred[sl]);
  __syncthreads();

  f32x4 ud = {0,0,0,0};
  const float* nxr = upd + sl * 128;
  for (int c = 0; c < 128; ++c)
    ud += *(const f32x4*)(Wv + c * 128 + jq) * nxr[c];
  *(f32x4*)(upd2 + t * 4) = ud;
  __syncthreads();

  f32x4 ir = {0,0,0,0}, iz = {0,0,0,0}, inn = {0,0,0,0};
  f32x4 hr = {0,0,0,0}, hz = {0,0,0,0}, hn = {0,0,0,0};
  const float* wih_p = wih + jq;
  const float* whh_p = whh + jq;
  const float* ur  = upd2 + sl * 128;
  const float* hrw = sp + sl * 128;
  for (int c = 0; c < 128; ++c) {
    float u = ur[c], h = hrw[c];
    ir  += *(const f32x4*)(wih_p + c * 384)       * u;
    iz  += *(const f32x4*)(wih_p + c * 384 + 128) * u;
    inn += *(const f32x4*)(wih_p + c * 384 + 256) * u;
    hr  += *(const f32x4*)(whh_p + c * 384)       * h;
    hz  += *(const f32x4*)(whh_p + c * 384 + 128) * h;
    hn  += *(const f32x4*)(whh_p + c * 384 + 256) * h;
  }
  ir  += *(const f32x4*)(bih + jq);
  iz  += *(const f32x4*)(bih + 128 + jq);
  inn += *(const f32x4*)(bih + 256 + jq);
  hr  += *(const f32x4*)(bhh + jq);
  hz  += *(const f32x4*)(bhh + 128 + jq);
  hn  += *(const f32x4*)(bhh + 256 + jq);
  f32x4 snew;
  #pragma unroll
  for (int i = 0; i < 4; ++i) {
    float r = sigf(ir[i] + hr[i]);
    float z = sigf(iz[i] + hz[i]);
    float n = tanhfast(inn[i] + r * hn[i]);
    snew[i] = (1.f - z) * n + z * hp4[i];
  }

  float ps = snew[0] + snew[1] + snew[2] + snew[3];
  float pq = snew[0]*snew[0] + snew[1]*snew[1] + snew[2]*snew[2] + snew[3]*snew[3];
  ps += __shfl_xor(ps, 1); ps += __shfl_xor(ps, 2); ps += __shfl_xor(ps, 4); ps += __shfl_xor(ps, 8); ps += __shfl_xor(ps, 16);
  pq += __shfl_xor(pq, 1); pq += __shfl_xor(pq, 2); pq += __shfl_xor(pq, 4); pq += __shfl_xor(pq, 8); pq += __shfl_xor(pq, 16);
  float mean = ps * (1.f / 128.f);
  float var  = pq * (1.f / 128.f) - mean * mean;
  float rstd = rsqrtf(var + 1e-5f);
  f32x4 lf = (snew - mean) * rstd * (*(const f32x4*)(lnfg + jq)) + (*(const f32x4*)(lnfb + jq));
  *(f32x4*)(lnb + t * 4) = lf;
  __syncthreads();

  f32x4 ha = {0,0,0,0};
  const float* w1p = w1 + jq;
  const float* lrow = lnb + sl * 128;
  for (int c = 0; c < 128; ++c)
    ha += *(const f32x4*)(w1p + c * 128) * lrow[c];
  ha += *(const f32x4*)(b1 + jq);
  #pragma unroll
  for (int i = 0; i < 4; ++i) ha[i] = fmaxf(ha[i], 0.f);
  *(f32x4*)(upd + t * 4) = ha;
  __syncthreads();

  f32x4 oa = {0,0,0,0};
  const float* w2p = w2 + jq;
  const float* hrow = upd + sl * 128;
  for (int c = 0; c < 128; ++c)
    oa += *(const f32x4*)(w2p + c * 128) * hrow[c];
  oa += *(const f32x4*)(b2 + jq);
  f32x4 sf = snew + oa;
  *(f32x4*)(sout + base + t * 4) = sf;

  if (doq) {
    float qs = sf[0] + sf[1] + sf[2] + sf[3];
    float qz = sf[0]*sf[0] + sf[1]*sf[1] + sf[2]*sf[2] + sf[3]*sf[3];
    qs += __shfl_xor(qs, 1); qs += __shfl_xor(qs, 2); qs += __shfl_xor(qs, 4); qs += __shfl_xor(qs, 8); qs += __shfl_xor(qs, 16);
    qz += __shfl_xor(qz, 1); qz += __shfl_xor(qz, 2); qz += __shfl_xor(qz, 4); qz += __shfl_xor(qz, 8); qz += __shfl_xor(qz, 16);
    float m2 = qs * (1.f / 128.f);
    float v2 = qz * (1.f / 128.f) - m2 * m2;
    float rs2 = rsqrtf(v2 + 1e-5f);
    f32x4 lq = (sf - m2) * rs2 * (*(const f32x4*)(lnsg + jq)) + (*(const f32x4*)(lnsb + jq));
    *(f32x4*)(sp + t * 4) = lq;
    __syncthreads();
    f32x4 qa = {0,0,0,0};
    const float* wqp = wqk + jq;
    const float* qrow = sp + sl * 128;
    for (int c = 0; c < 128; ++c)
      qa += *(const f32x4*)(wqp + c * 128) * qrow[c];
    qa *= 0.08838834764831845f;
    u32x2 pk = { pkbf(qa[0], qa[1]), pkbf(qa[2], qa[3]) };
    *(u32x2*)(qout + base + t * 4) = pk;
  }
}

extern "C" void kernel_launch(void* const* d_in, const int* in_sizes, int n_in,
                              void* d_out, int out_size, void* d_ws, size_t ws_size,
                              hipStream_t stream) {
  (void)in_sizes; (void)n_in; (void)out_size; (void)ws_size;
  const float* slots = (const float*)d_in[0];
  const float* inputs = (const float*)d_in[1];
  const float* Wq  = (const float*)d_in[2];
  const float* Wk  = (const float*)d_in[3];
  const float* Wv  = (const float*)d_in[4];
  const float* wih = (const float*)d_in[5];
  const float* whh = (const float*)d_in[6];
  const float* bih = (const float*)d_in[7];
  const float* bhh = (const float*)d_in[8];
  const float* w1  = (const float*)d_in[9];
  const float* b1  = (const float*)d_in[10];
  const float* w2  = (const float*)d_in[11];
  const float* b2  = (const float*)d_in[12];
  const float* lnig = (const float*)d_in[13];
  const float* lnib = (const float*)d_in[14];
  const float* lnsg = (const float*)d_in[15];
  const float* lnsb = (const float*)d_in[16];
  const float* lnfg = (const float*)d_in[17];
  const float* lnfb = (const float*)d_in[18];

  char* ws = (char*)d_ws;
  unsigned short* xln  = (unsigned short*)(ws);
  unsigned short* qbuf = (unsigned short*)(ws + 134217728L);
  float* wqk  = (float*)(ws + 134348800L);
  float* nump = (float*)(ws + 134414336L);
  float* denp = (float*)(ws + 151191552L);
  float* sbuf = (float*)(ws + 151322624L);

  k0_wqk<<<64, 256, 0, stream>>>(Wq, Wk, wqk);
  k1_ln<<<8192, 256, 0, stream>>>(inputs, lnig, lnib, xln);
  kq_init<<<32, 512, 0, stream>>>(slots, lnsg, lnsb, wqk, qbuf);
  for (int it = 0; it < 3; ++it) {
    k2_attn<<<dim3(32, 32), 256, 0, stream>>>(xln, qbuf, nump, denp);
    const float* sprev = (it == 0) ? slots : sbuf;
    float* sdst = (it == 2) ? (float*)d_out : sbuf;
    k3_update<<<dim3(4, 32), 128, 0, stream>>>(sprev, nump, denp, Wv,
                                      wih, whh, bih, bhh, w1, b1, w2, b2,
                                      lnfg, lnfb, lnsg, lnsb, wqk,
                                      sdst, qbuf, (it < 2) ? 1 : 0);
  }
}